// Round 1
// baseline (855.375 us; speedup 1.0000x reference)
//
#include <hip/hip_runtime.h>

namespace {

constexpr int Bn = 16;
constexpr int Nn = 2048;
constexpr int Dn = 512;
constexpr int BK = 32;

typedef _Float16 h4 __attribute__((ext_vector_type(4)));
typedef _Float16 h8 __attribute__((ext_vector_type(8)));
typedef float    fx4 __attribute__((ext_vector_type(4)));

__device__ __forceinline__ unsigned encf(float x){
  unsigned u = __float_as_uint(x);
  return (u & 0x80000000u) ? ~u : (u | 0x80000000u);
}
__device__ __forceinline__ float decf(unsigned u){
  return (u & 0x80000000u) ? __uint_as_float(u & 0x7fffffffu) : __uint_as_float(~u);
}

// Stage a 128x32 tile into LDS as [128][BK] f16.
// MODE 0: f16 source.  MODE 1: f32 source -> f16.  MODE 2: f32 L + exp(v-kmax[k])*kinv[k].
template<int MODE>
__device__ __forceinline__ void stage_tile(const void* __restrict__ gbase, int ld,
    int row0, int k0, _Float16* __restrict__ lds, int t,
    const float* __restrict__ kmax, const float* __restrict__ kinv)
{
  if constexpr (MODE == 0) {
    const _Float16* g = (const _Float16*)gbase;
    #pragma unroll
    for (int rd = 0; rd < 2; ++rd) {
      int h = rd*2048 + t*8;
      int r = h >> 5, c = h & 31;
      h8 v = *(const h8*)(g + (long)(row0 + r)*ld + k0 + c);
      *(h8*)(lds + r*BK + c) = v;
    }
  } else {
    const float* g = (const float*)gbase;
    #pragma unroll
    for (int rd = 0; rd < 4; ++rd) {
      int f = rd*1024 + t*4;
      int r = f >> 5, c = f & 31;
      fx4 v = *(const fx4*)(g + (long)(row0 + r)*ld + k0 + c);
      h4 o;
      if constexpr (MODE == 2) {
        fx4 cm = *(const fx4*)(kmax + k0 + c);
        fx4 ci = *(const fx4*)(kinv + k0 + c);
        #pragma unroll
        for (int i = 0; i < 4; ++i) o[i] = (_Float16)(__expf(v[i] - cm[i]) * ci[i]);
      } else {
        #pragma unroll
        for (int i = 0; i < 4; ++i) o[i] = (_Float16)v[i];
      }
      *(h4*)(lds + r*BK + c) = o;
    }
  }
}

// BT GEMM: C[i][j] = sum_k A[i][k] * B[j][k], 128x128 tile, 4 waves (each 64x64).
// EPI 0: f32 store. EPI 1: f32 store + row/col atomicMax (encoded). EPI 2: f16 dual store (C row-major + C2 transposed).
template<int MA, int MB, int EPI>
__global__ __launch_bounds__(256) void gemm_bt(
    const void* __restrict__ Ap, long sA,
    const void* __restrict__ Bp, long sB,
    void* __restrict__ Cp, long sC, int ldc,
    void* __restrict__ C2p, long sC2, int ldc2,
    int lda, int ldb, int K,
    const float* __restrict__ kmax, const float* __restrict__ kinv, long sKst,
    unsigned* __restrict__ rmaxU, unsigned* __restrict__ cmaxU, long sStat)
{
  constexpr int SH = (EPI == 2) ? (128*136) : (2*128*BK);
  __shared__ _Float16 smem[SH];
  _Float16* lA = smem;
  _Float16* lB = smem + 128*BK;

  const int b = blockIdx.z;
  const int row0 = blockIdx.x * 128;
  const int col0 = blockIdx.y * 128;
  const int t = threadIdx.x;
  const int w = t >> 6, l = t & 63;
  const int wr = w >> 1, wc = w & 1;
  const int l15 = l & 15, lg = l >> 4;

  const void* Ab;
  const void* Bb;
  if constexpr (MA == 0) Ab = (const void*)((const _Float16*)Ap + (long)b * sA);
  else                   Ab = (const void*)((const float*)Ap + (long)b * sA);
  if constexpr (MB == 0) Bb = (const void*)((const _Float16*)Bp + (long)b * sB);
  else                   Bb = (const void*)((const float*)Bp + (long)b * sB);

  const float* km = nullptr; const float* ki = nullptr;
  if constexpr (MA == 2) { km = kmax + (long)b * sKst; ki = kinv + (long)b * sKst; }

  fx4 acc[4][4];
  #pragma unroll
  for (int fi = 0; fi < 4; ++fi)
    #pragma unroll
    for (int fj = 0; fj < 4; ++fj)
      acc[fi][fj] = (fx4){0.f, 0.f, 0.f, 0.f};

  for (int k0 = 0; k0 < K; k0 += BK) {
    __syncthreads();
    stage_tile<MA>(Ab, lda, row0, k0, lA, t, km, ki);
    stage_tile<MB>(Bb, ldb, col0, k0, lB, t, nullptr, nullptr);
    __syncthreads();
    h8 af[4], bf[4];
    #pragma unroll
    for (int fi = 0; fi < 4; ++fi)
      af[fi] = *(const h8*)(lA + (wr*64 + fi*16 + l15)*BK + lg*8);
    #pragma unroll
    for (int fj = 0; fj < 4; ++fj)
      bf[fj] = *(const h8*)(lB + (wc*64 + fj*16 + l15)*BK + lg*8);
    #pragma unroll
    for (int fi = 0; fi < 4; ++fi)
      #pragma unroll
      for (int fj = 0; fj < 4; ++fj)
        acc[fi][fj] = __builtin_amdgcn_mfma_f32_16x16x32_f16(af[fi], bf[fj], acc[fi][fj], 0, 0, 0);
  }

  if constexpr (EPI <= 1) {
    float* Cb = (float*)Cp + (long)b * sC;
    #pragma unroll
    for (int fi = 0; fi < 4; ++fi)
      #pragma unroll
      for (int fj = 0; fj < 4; ++fj)
        #pragma unroll
        for (int j = 0; j < 4; ++j)
          Cb[(long)(row0 + wr*64 + fi*16 + lg*4 + j)*ldc + col0 + wc*64 + fj*16 + l15] = acc[fi][fj][j];

    if constexpr (EPI == 1) {
      // row maxes: per lane, max over fj; butterfly over low 4 lane bits
      float rp[4][4];
      #pragma unroll
      for (int fi = 0; fi < 4; ++fi)
        #pragma unroll
        for (int j = 0; j < 4; ++j)
          rp[fi][j] = fmaxf(fmaxf(acc[fi][0][j], acc[fi][1][j]),
                            fmaxf(acc[fi][2][j], acc[fi][3][j]));
      #pragma unroll
      for (int m = 1; m < 16; m <<= 1)
        #pragma unroll
        for (int fi = 0; fi < 4; ++fi)
          #pragma unroll
          for (int j = 0; j < 4; ++j)
            rp[fi][j] = fmaxf(rp[fi][j], __shfl_xor(rp[fi][j], m, 64));
      if (l15 == 0) {
        unsigned* rmb = rmaxU + (long)b * sStat;
        #pragma unroll
        for (int fi = 0; fi < 4; ++fi)
          #pragma unroll
          for (int j = 0; j < 4; ++j)
            atomicMax(rmb + row0 + wr*64 + fi*16 + lg*4 + j, encf(rp[fi][j]));
      }
      // col maxes: per lane, max over fi,j; butterfly over lane-group bits
      float cp[4];
      #pragma unroll
      for (int fj = 0; fj < 4; ++fj) {
        float v = -3.4e38f;
        #pragma unroll
        for (int fi = 0; fi < 4; ++fi)
          #pragma unroll
          for (int j = 0; j < 4; ++j)
            v = fmaxf(v, acc[fi][fj][j]);
        cp[fj] = v;
      }
      #pragma unroll
      for (int fj = 0; fj < 4; ++fj) {
        cp[fj] = fmaxf(cp[fj], __shfl_xor(cp[fj], 16, 64));
        cp[fj] = fmaxf(cp[fj], __shfl_xor(cp[fj], 32, 64));
      }
      if (lg == 0) {
        unsigned* cmb = cmaxU + (long)b * sStat;
        #pragma unroll
        for (int fj = 0; fj < 4; ++fj)
          atomicMax(cmb + col0 + wc*64 + fj*16 + l15, encf(cp[fj]));
      }
    }
  } else {
    // EPI 2: f16 dual store via LDS transpose
    __syncthreads();
    #pragma unroll
    for (int fi = 0; fi < 4; ++fi)
      #pragma unroll
      for (int fj = 0; fj < 4; ++fj)
        #pragma unroll
        for (int j = 0; j < 4; ++j)
          smem[(wr*64 + fi*16 + lg*4 + j)*136 + wc*64 + fj*16 + l15] = (_Float16)acc[fi][fj][j];
    __syncthreads();
    _Float16* Qb  = (_Float16*)Cp  + (long)b * sC;
    _Float16* QTb = (_Float16*)C2p + (long)b * sC2;
    #pragma unroll
    for (int rd = 0; rd < 8; ++rd) {
      int r = rd*16 + (t >> 4);
      int c8 = (t & 15)*8;
      h8 v = *(const h8*)(smem + r*136 + c8);
      *(h8*)(Qb + (long)(row0 + r)*ldc + col0 + c8) = v;
    }
    #pragma unroll
    for (int rd = 0; rd < 8; ++rd) {
      int dl = rd*16 + (t >> 4);
      int n8 = (t & 15)*8;
      h8 v;
      #pragma unroll
      for (int i = 0; i < 8; ++i) v[i] = smem[(n8 + i)*136 + dl];
      *(h8*)(QTb + (long)(col0 + dl)*ldc2 + row0 + n8) = v;
    }
  }
}

// x2 f32 -> x2h f16 (row-major) + x2hT f16 (transposed) per batch
__global__ __launch_bounds__(256) void convert_x2(const float* __restrict__ x2,
    _Float16* __restrict__ x2h, _Float16* __restrict__ x2hT)
{
  __shared__ _Float16 lt[64*66];
  const int b = blockIdx.z, m0 = blockIdx.x*64, d0 = blockIdx.y*64;
  const int t = threadIdx.x;
  const float* xb = x2 + (long)b*Nn*Dn;
  _Float16* hb = x2h + (long)b*Nn*Dn;
  #pragma unroll
  for (int rd = 0; rd < 4; ++rd) {
    int r = rd*16 + (t >> 4), c = (t & 15)*4;
    fx4 v = *(const fx4*)(xb + (long)(m0 + r)*Dn + d0 + c);
    h4 h;
    #pragma unroll
    for (int i = 0; i < 4; ++i) { h[i] = (_Float16)v[i]; lt[r*66 + c + i] = h[i]; }
    *(h4*)(hb + (long)(m0 + r)*Dn + d0 + c) = h;
  }
  __syncthreads();
  _Float16* tb = x2hT + (long)b*Dn*Nn;
  #pragma unroll
  for (int rd = 0; rd < 4; ++rd) {
    int dl = rd*16 + (t >> 4), ml = (t & 15)*4;
    h4 h;
    #pragma unroll
    for (int i = 0; i < 4; ++i) h[i] = lt[(ml + i)*66 + dl];
    *(h4*)(tb + (long)(d0 + dl)*Nn + m0 + ml) = h;
  }
}

__global__ __launch_bounds__(256) void decode_maxes(const unsigned* __restrict__ ru,
    const unsigned* __restrict__ cu, float* __restrict__ rf, float* __restrict__ cf, int n)
{
  int i = blockIdx.x*256 + threadIdx.x;
  if (i < n) { rf[i] = decf(ru[i]); cf[i] = decf(cu[i]); }
}

// per 256x256 tile: rowsum += sum_m exp(L-rmax[row]); colsum += sum_n exp(L-cmax[col])
__global__ __launch_bounds__(256) void softmax_sums(const float* __restrict__ L,
    const float* __restrict__ rmaxF, const float* __restrict__ cmaxF,
    float* __restrict__ rsum, float* __restrict__ csum)
{
  const int b = blockIdx.z, r0 = blockIdx.x*256, c0 = blockIdx.y*256;
  const int t = threadIdx.x, w = t >> 6, l = t & 63;
  const float* Lb = L + (long)b*Nn*Nn;
  fx4 cm = *(const fx4*)(cmaxF + (long)b*Nn + c0 + l*4);
  float ca0 = 0.f, ca1 = 0.f, ca2 = 0.f, ca3 = 0.f;
  for (int it = 0; it < 64; ++it) {
    int row = r0 + it*4 + w;
    fx4 v = *(const fx4*)(Lb + (long)row*Nn + c0 + l*4);
    float rm = rmaxF[(long)b*Nn + row];
    float s = __expf(v[0]-rm) + __expf(v[1]-rm) + __expf(v[2]-rm) + __expf(v[3]-rm);
    ca0 += __expf(v[0]-cm[0]); ca1 += __expf(v[1]-cm[1]);
    ca2 += __expf(v[2]-cm[2]); ca3 += __expf(v[3]-cm[3]);
    #pragma unroll
    for (int m = 1; m < 64; m <<= 1) s += __shfl_xor(s, m, 64);
    if (l == 0) atomicAdd(rsum + (long)b*Nn + row, s);
  }
  atomicAdd(csum + (long)b*Nn + c0 + l*4 + 0, ca0);
  atomicAdd(csum + (long)b*Nn + c0 + l*4 + 1, ca1);
  atomicAdd(csum + (long)b*Nn + c0 + l*4 + 2, ca2);
  atomicAdd(csum + (long)b*Nn + c0 + l*4 + 3, ca3);
}

__global__ __launch_bounds__(256) void invert_sums(const float* __restrict__ rs,
    const float* __restrict__ cs, float* __restrict__ ri, float* __restrict__ ci, int n)
{
  int i = blockIdx.x*256 + threadIdx.x;
  if (i < n) { ri[i] = 1.f / rs[i]; ci[i] = 1.f / cs[i]; }
}

// Read L 64x64 tile; write normalized A_D in place; write A_Q (f32) and At (f16) transposed.
__global__ __launch_bounds__(256) void finalize(float* __restrict__ AD, float* __restrict__ AQ,
    _Float16* __restrict__ At,
    const float* __restrict__ rmaxF, const float* __restrict__ rinv,
    const float* __restrict__ cmaxF, const float* __restrict__ cinv)
{
  __shared__ float l2[64*65];
  __shared__ _Float16 l1[64*66];
  const int b = blockIdx.z, n0 = blockIdx.x*64, m0 = blockIdx.y*64;
  const int t = threadIdx.x;
  float* Lb = AD + (long)b*Nn*Nn;
  #pragma unroll
  for (int rd = 0; rd < 4; ++rd) {
    int r = rd*16 + (t >> 4), c = (t & 15)*4;
    long off = (long)(n0 + r)*Nn + m0 + c;
    fx4 v = *(const fx4*)(Lb + off);
    float rm = rmaxF[(long)b*Nn + n0 + r];
    float ri = rinv [(long)b*Nn + n0 + r];
    fx4 cm = *(const fx4*)(cmaxF + (long)b*Nn + m0 + c);
    fx4 ci = *(const fx4*)(cinv  + (long)b*Nn + m0 + c);
    fx4 e1;
    #pragma unroll
    for (int i = 0; i < 4; ++i) {
      e1[i] = __expf(v[i] - rm) * ri;
      float e2 = __expf(v[i] - cm[i]) * ci[i];
      l2[r*65 + c + i] = e2;
      l1[r*66 + c + i] = (_Float16)e1[i];
    }
    *(fx4*)(Lb + off) = e1;   // A_D in place
  }
  __syncthreads();
  float* Qb = AQ + (long)b*Nn*Nn;
  _Float16* Atb = At + (long)b*Nn*Nn;
  #pragma unroll
  for (int rd = 0; rd < 4; ++rd) {
    int ml = rd*16 + (t >> 4), nl = (t & 15)*4;
    fx4 q; h4 h;
    #pragma unroll
    for (int i = 0; i < 4; ++i) { q[i] = l2[(nl + i)*65 + ml]; h[i] = l1[(nl + i)*66 + ml]; }
    *(fx4*)(Qb + (long)(m0 + ml)*Nn + n0 + nl) = q;
    *(h4*)(Atb + (long)(m0 + ml)*Nn + n0 + nl) = h;
  }
}

} // namespace

extern "C" void kernel_launch(void* const* d_in, const int* in_sizes, int n_in,
                              void* d_out, int out_size, void* d_ws, size_t ws_size,
                              hipStream_t stream)
{
  const float* x1 = (const float*)d_in[0];
  const float* x2 = (const float*)d_in[1];
  // d_in[2] = node_mask: unused by reference
  const float* Wq = (const float*)d_in[3];

  float* out = (float*)d_out;
  float* C_Q = out;
  float* C_D = out + (long)Bn*Nn*Dn;
  float* A_D = out + 2L*Bn*Nn*Dn;   // doubles as L buffer until finalize
  float* A_Q = A_D + (long)Bn*Nn*Nn;

  char* ws = (char*)d_ws;
  _Float16* Qh   = (_Float16*)ws;  ws += sizeof(_Float16)*(long)Bn*Nn*Dn;
  _Float16* QhT  = (_Float16*)ws;  ws += sizeof(_Float16)*(long)Bn*Dn*Nn;
  _Float16* x2h  = (_Float16*)ws;  ws += sizeof(_Float16)*(long)Bn*Nn*Dn;
  _Float16* x2hT = (_Float16*)ws;  ws += sizeof(_Float16)*(long)Bn*Dn*Nn;
  _Float16* At   = (_Float16*)ws;  ws += sizeof(_Float16)*(long)Bn*Nn*Nn;
  unsigned* rmaxU = (unsigned*)ws;
  unsigned* cmaxU = rmaxU + (long)Bn*Nn;
  float* rsum  = (float*)(cmaxU + (long)Bn*Nn);
  float* csum  = rsum  + (long)Bn*Nn;
  float* rmaxF = csum  + (long)Bn*Nn;
  float* cmaxF = rmaxF + (long)Bn*Nn;
  float* rinv  = cmaxF + (long)Bn*Nn;
  float* cinv  = rinv  + (long)Bn*Nn;

  // zero rmaxU, cmaxU, rsum, csum (contiguous)
  hipMemsetAsync(rmaxU, 0, 4*sizeof(float)*(long)Bn*Nn, stream);

  dim3 blk(256);

  // K0: x2 -> f16 + transposed
  convert_x2<<<dim3(32, 8, 16), blk, 0, stream>>>(x2, x2h, x2hT);

  // K1: Q = x1 @ Wq^T  -> Qh (f16) + QhT (f16 transposed)
  gemm_bt<1,1,2><<<dim3(16, 4, 16), blk, 0, stream>>>(
      x1, (long)Nn*Dn, Wq, 0L,
      Qh, (long)Nn*Dn, Dn, QhT, (long)Dn*Nn, Nn,
      Dn, Dn, Dn,
      nullptr, nullptr, 0, nullptr, nullptr, 0);

  // K2: L = Qh @ x2h^T -> A_D region (f32) + row/col atomicMax
  gemm_bt<0,0,1><<<dim3(16, 16, 16), blk, 0, stream>>>(
      Qh, (long)Nn*Dn, x2h, (long)Nn*Dn,
      A_D, (long)Nn*Nn, Nn, nullptr, 0L, 0,
      Dn, Dn, Dn,
      nullptr, nullptr, 0, rmaxU, cmaxU, Nn);

  // K2b: decode encoded maxes
  decode_maxes<<<dim3((Bn*Nn + 255)/256), blk, 0, stream>>>(rmaxU, cmaxU, rmaxF, cmaxF, Bn*Nn);

  // K3: exp sums over both axes
  softmax_sums<<<dim3(8, 8, 16), blk, 0, stream>>>(A_D, rmaxF, cmaxF, rsum, csum);

  // K3b: reciprocals
  invert_sums<<<dim3((Bn*Nn + 255)/256), blk, 0, stream>>>(rsum, csum, rinv, cinv, Bn*Nn);

  // K6: C_Q = colsoftmax(L) @ x2  (reads L BEFORE finalize overwrites it; exp fused in staging)
  gemm_bt<2,0,0><<<dim3(16, 4, 16), blk, 0, stream>>>(
      A_D, (long)Nn*Nn, x2hT, (long)Dn*Nn,
      C_Q, (long)Nn*Dn, Dn, nullptr, 0L, 0,
      Nn, Nn, Nn,
      cmaxF, cinv, Nn, nullptr, nullptr, 0);

  // K4: normalized A_D in place, A_Q transposed, At = A_D^T f16
  finalize<<<dim3(32, 32, 16), blk, 0, stream>>>(A_D, A_Q, At, rmaxF, rinv, cmaxF, cinv);

  // K5: C_D = A_D^T @ Q
  gemm_bt<0,0,0><<<dim3(16, 4, 16), blk, 0, stream>>>(
      At, (long)Nn*Nn, QhT, (long)Dn*Nn,
      C_D, (long)Nn*Dn, Dn, nullptr, 0L, 0,
      Nn, Nn, Nn,
      nullptr, nullptr, 0, nullptr, nullptr, 0);
}